// Round 17
// baseline (275.356 us; speedup 1.0000x reference)
//
#include <hip/hip_runtime.h>

// ---------------- problem constants ----------------------------------------
#define NVOX 12000
#define NPTS 32
#define CIN  5
#define C1   64
#define C2   128
#define GD   16
#define GH   128
#define GW   128
#define SP   (GD*GH*GW)
static constexpr float EPSBN = 1e-5f;

typedef unsigned short ushortT;
typedef __attribute__((ext_vector_type(8))) short bf16x8;
typedef __attribute__((ext_vector_type(4))) float f32x4;

__device__ inline ushortT f2bf(float f) {
    unsigned int x = __float_as_uint(f);
    unsigned int r = (x + 0x7FFFu + ((x >> 16) & 1u)) >> 16;   // RNE
    return (ushortT)r;
}
__device__ inline float bf2f(ushortT u) { return __uint_as_float(((unsigned int)u) << 16); }

__device__ inline void gload16(const ushortT* g, ushortT* l) {
    __builtin_amdgcn_global_load_lds(
        (const __attribute__((address_space(1))) unsigned int*)g,
        (__attribute__((address_space(3))) unsigned int*)l, 16, 0, 0);
}

// padded spatial dims (channels-LAST layouts: [pos][C]) for conv2/conv3 inputs
#define P2D 10
#define P2H 66
#define P2W 66
#define PSP2 (P2D*P2H*P2W)
#define P3D 6
#define P3H 34
#define P3W 34
#define PSP3 (P3D*P3H*P3W)

// NOTE: biases are exact no-ops under training-mode BN (mean-subtracted).

// ---------------- prep: weight convert + vfe1 stats + scatter ---------------
// wb (BK=128): per phase a linear tile of TCO*16 chunks (16B); chunk p=(col,cp):
// content = w[cob*TCO+col][ci=(cp^(col&7))*8+j [+128 for CI=256 odd phase]]
__device__ inline void conv_w_one(const float* cw, ushortT* wb, int CI_, int TCO_,
                                  int NS_, int e) {
    int j = e & 7;
    int rest = e >> 3;
    int CHN = TCO_*16;
    int p = rest % CHN; int r = rest / CHN;
    int s = r % NS_;    int cob = r / NS_;
    int col = p >> 4, cp = p & 15;
    int cl = cp ^ (col & 7);
    int tap = (CI_==256) ? (s>>1) : s;
    int cib = (CI_==256) ? ((s&1)*128) : 0;
    int co = cob*TCO_ + col;
    int ci = cib + cl*8 + j;
    wb[e] = f2bf(cw[((size_t)co*CI_ + ci)*27 + tap]);
}

__global__ void prep(const float* __restrict__ x, const float* __restrict__ w1,
                     float* __restrict__ s1sum,
                     const float* __restrict__ cw1, const float* __restrict__ cw2,
                     const float* __restrict__ cw3, ushortT* __restrict__ wb1,
                     ushortT* __restrict__ wb2, ushortT* __restrict__ wb3,
                     const int* __restrict__ coords, int* __restrict__ winner) {
    __shared__ float s_w[CIN*C1];
    __shared__ float s_red[2][4][C1];
    const int blk = blockIdx.x;
    const int t = threadIdx.x;
    if (blk < 960) {
        for (int i = t; i < CIN*C1; i += 256) s_w[i] = w1[i];
        __syncthreads();
        int ch = t & 63, rr = t >> 6;
        float sum = 0.f, sq = 0.f;
        const int NROWS = NVOX * NPTS;
        for (int row = blk*4 + rr; row < NROWS; row += 960*4) {
            const float* xr = x + row*CIN;
            float y = 0.f;
            #pragma unroll
            for (int c = 0; c < CIN; ++c) y += xr[c] * s_w[c*C1 + ch];
            sum += y; sq += y*y;
        }
        s_red[0][rr][ch] = sum; s_red[1][rr][ch] = sq;
        __syncthreads();
        if (rr == 0) {
            sum = s_red[0][0][ch]+s_red[0][1][ch]+s_red[0][2][ch]+s_red[0][3][ch];
            sq  = s_red[1][0][ch]+s_red[1][1][ch]+s_red[1][2][ch]+s_red[1][3][ch];
            atomicAdd(&s1sum[ch], sum);
            atomicAdd(&s1sum[C1+ch], sq);
        }
    } else if (blk < 1984) {
        const int N1 = 442368, N2 = 884736, N3 = 1769472;
        const int total = N1+N2+N3;
        for (int e0 = (blk-960)*256 + t; e0 < total; e0 += 1024*256) {
            if (e0 < N1)         conv_w_one(cw1, wb1, 128, 128, 27, e0);
            else if (e0 < N1+N2) conv_w_one(cw2, wb2, 128, 64,  27, e0-N1);
            else                 conv_w_one(cw3, wb3, 256, 64,  54, e0-N1-N2);
        }
    } else {
        int v = (blk-1984)*256 + t;
        if (v < NVOX) {
            int d = coords[v*3+0], h = coords[v*3+1], w = coords[v*3+2];
            atomicMax(&winner[(d*GH + h)*GW + w], v + 1);   // 0 = empty
        }
    }
}

// ---------------- fused VFE1-apply + VFE2-linear (16 voxels / block) --------
__global__ void vfe12(const float* __restrict__ x, const float* __restrict__ w1,
                      const float* __restrict__ sums1, const float* __restrict__ g1,
                      const float* __restrict__ be1, const float* __restrict__ w2,
                      float* __restrict__ y2, float* __restrict__ s2sum) {
    __shared__ float s_w1[CIN*C1];        // 320
    __shared__ float s_x[16*NPTS*CIN];    // 2560
    __shared__ float s_f[16*C1];          // 1024
    __shared__ float s_w2[C2][68];        // 8704
    int v0 = blockIdx.x*16, t = threadIdx.x;   // 256 threads
    for (int i = t; i < CIN*C1; i += 256) s_w1[i] = w1[i];
    for (int i = t; i < C1*C2; i += 256) { int c = i >> 7, o = i & 127; s_w2[o][c] = w2[i]; }
    for (int i = t; i < 16*NPTS*CIN; i += 256) s_x[i] = x[(size_t)v0*NPTS*CIN + i];
    int ch = t & 63;
    const float invN1 = 1.f/(NVOX*NPTS);
    float mean = sums1[ch]*invN1;
    float var  = sums1[C1+ch]*invN1 - mean*mean;
    float sc = g1[ch]*rsqrtf(var + EPSBN);
    float sh = be1[ch] - mean*sc;
    __syncthreads();
    // VFE1: thread (sub=t>>6, ch) handles voxels sub, sub+4, sub+8, sub+12
    #pragma unroll
    for (int k = 0; k < 4; ++k) {
        int vl = (t >> 6) + k*4;
        const float* xs = s_x + vl*NPTS*CIN;
        float m = 0.f;
        for (int p = 0; p < NPTS; ++p) {
            float y = 0.f;
            #pragma unroll
            for (int c = 0; c < CIN; ++c) y += xs[p*CIN+c]*s_w1[c*C1+ch];
            m = fmaxf(m, y*sc + sh);
        }
        s_f[vl*C1 + ch] = m;
    }
    __syncthreads();
    // VFE2: thread (o=t&127, half=t>>7) handles 8 voxels
    int o = t & 127, half = t >> 7;
    float sum = 0.f, sq = 0.f;
    for (int vl = half*8; vl < half*8 + 8; ++vl) {
        float y = 0.f;
        #pragma unroll
        for (int c4 = 0; c4 < C1; c4 += 4) {
            float4 f = *(const float4*)&s_f[vl*C1 + c4];
            float4 w = *(const float4*)&s_w2[o][c4];
            y += f.x*w.x + f.y*w.y + f.z*w.z + f.w*w.w;
        }
        y2[(v0+vl)*C2 + o] = y;
        sum += y; sq += y*y;
    }
    atomicAdd(&s2sum[o], sum);
    atomicAdd(&s2sum[C2+o], sq);
}

__global__ void vfe2_apply_bf16(const float* __restrict__ y2, const float* __restrict__ sums,
                                const float* __restrict__ g, const float* __restrict__ be,
                                ushortT* __restrict__ f2b) {
    __shared__ float s_sc[C2], s_sh[C2];
    int t = threadIdx.x;
    if (t < C2) {
        const float invN = 1.f/NVOX;
        float mean = sums[t]*invN;
        float var  = sums[C2+t]*invN - mean*mean;
        float sc = g[t]*rsqrtf(var + EPSBN);
        s_sc[t] = sc; s_sh[t] = be[t] - mean*sc;
    }
    __syncthreads();
    int i = blockIdx.x*256 + t;
    if (i >= NVOX*C2/4) return;
    const float4 v = *(const float4*)(y2 + (size_t)i*4);
    int c0 = (i*4) & (C2-1);
    ushort4 o;
    o.x = f2bf(fmaxf(0.f, v.x*s_sc[c0+0]+s_sh[c0+0]));
    o.y = f2bf(fmaxf(0.f, v.y*s_sc[c0+1]+s_sh[c0+1]));
    o.z = f2bf(fmaxf(0.f, v.z*s_sc[c0+2]+s_sh[c0+2]));
    o.w = f2bf(fmaxf(0.f, v.w*s_sc[c0+3]+s_sh[c0+3]));
    *(ushort4*)(f2b + (size_t)i*4) = o;
}

// ---------------- conv3d as tap-GEMM (m97 skeleton; R10/R16-proven) ---------
// GATHER mode (conv1): s_x sources are PER-LANE gathers from f2b (in_p is
// pre-offset by -128 so winner+1 indexes directly); empty/pad -> zero page.
template<int CI, int CO, int TILE_CO, int TILE_SP, int THREADS,
         int PD, int PH, int PW, int DO, int HO, int WO,
         int OPH, int OPW, int NS, int NSLICE, bool ATOMIC, bool GATHER>
__global__ __launch_bounds__(THREADS) void conv3d_mfma(
        const ushortT* __restrict__ in_p, const ushortT* __restrict__ wb,
        void* __restrict__ outp, float* __restrict__ sums_out,
        const int* __restrict__ winner, const ushortT* __restrict__ zerop) {
    constexpr int NW      = THREADS/64;
    constexpr int WAVES_M = TILE_CO/32;
    constexpr int WAVES_N = NW/WAVES_M;
    constexpr int FRAG_N  = TILE_SP/(WAVES_N*16);
    constexpr int TILE_Y  = TILE_SP/8;
    constexpr int SPB     = NS/NSLICE;
    constexpr int WCH     = TILE_CO*16;
    constexpr int NHALO   = 3*(2*TILE_Y+1)*17;

    __shared__ ushortT s_x[2][TILE_SP*128];
    __shared__ ushortT s_w[2][TILE_CO*128];
    __shared__ short   s_wn[GATHER ? NHALO : 2];

    constexpr int nbx = WO/8, nby = HO/TILE_Y;
    constexpr int NWG = nbx*nby*DO*(CO/TILE_CO)*NSLICE;
    int b = (blockIdx.x & 7)*(NWG >> 3) + (blockIdx.x >> 3);   // XCD swizzle
    const int bx = b % nbx; b /= nbx;
    const int by = b % nby; b /= nby;
    const int bz = b % DO;  b /= DO;
    const int cob   = b % (CO/TILE_CO);
    const int slice = b / (CO/TILE_CO);
    const int co0 = cob*TILE_CO;
    const int oy0 = by*TILE_Y, ox0 = bx*8;
    const int t = threadIdx.x;
    const int lane = t & 63, wid = t >> 6;
    const int lr = lane & 15, lq = lane >> 4;
    const int wm = wid % WAVES_M, wn = wid / WAVES_M;

    if constexpr (GATHER) {
        constexpr int HROW = 2*TILE_Y+1;
        for (int c = t; c < NHALO; c += THREADS) {
            int zz = c/(HROW*17), rr = c%(HROW*17), yy = rr/17, xx = rr%17;
            int iz = 2*bz-1+zz, iy = 2*oy0-1+yy, ix = 2*ox0-1+xx;
            int wv = 0;
            if ((unsigned)iz < (unsigned)GD && (unsigned)iy < (unsigned)GH &&
                (unsigned)ix < (unsigned)GW)
                wv = winner[(iz*GH + iy)*GW + ix];
            s_wn[c] = (short)wv;
        }
        __syncthreads();
    }

    // per-thread input-staging invariants
    size_t xpre[4]; int xbase[4]; int cl8[4];
    #pragma unroll
    for (int j = 0; j < 4; ++j) {
        int q = t + j*THREADS;
        int n = q >> 4, cp = q & 15;
        int cl = cp ^ (n & 7);
        int oy = n >> 3, ox = n & 7;
        if constexpr (GATHER) {
            xbase[j] = (2*oy)*17 + 2*ox;
            cl8[j]   = cl*8;
            xpre[j]  = 0;
        } else {
            xpre[j] = (size_t)(((2*bz)*PH + (2*oy0 + 2*oy))*PW + (2*ox0 + 2*ox))*CI + cl*8;
            xbase[j] = 0; cl8[j] = 0;
        }
    }
    // compute-side row bases
    int aoff[2], axr[2], boff[FRAG_N], bxr[FRAG_N];
    #pragma unroll
    for (int f = 0; f < 2; ++f) {
        int c = wm*32 + f*16 + lr;
        aoff[f] = c*128; axr[f] = c & 7;
    }
    #pragma unroll
    for (int f = 0; f < FRAG_N; ++f) {
        int n = wn*(FRAG_N*16) + f*16 + lr;
        boff[f] = n*128; bxr[f] = n & 7;
    }

    f32x4 acc[2][FRAG_N];
    #pragma unroll
    for (int i = 0; i < 2; ++i)
        #pragma unroll
        for (int j = 0; j < FRAG_N; ++j) acc[i][j] = (f32x4){0.f,0.f,0.f,0.f};

    const int s0 = slice*SPB;

#define STAGE(bufi, s) { \
    const int tap_ = (CI==256) ? ((s)>>1) : (s); \
    const int cib_ = (CI==256) ? (((s)&1)*128) : 0; \
    const int kz_ = tap_/9, ky_ = (tap_/3)%3, kx_ = tap_%3; \
    const ushortT* wsrc_ = wb + ((size_t)(cob*NS + (s)))*(WCH*8); \
    _Pragma("unroll") for (int j = 0; j < 4; ++j) \
        gload16(wsrc_ + (size_t)(t + j*THREADS)*8, &s_w[bufi][(wid*64 + j*THREADS)*8]); \
    if constexpr (GATHER) { \
        const int poff_ = kz_*((2*TILE_Y+1)*17) + ky_*17 + kx_; \
        _Pragma("unroll") for (int j = 0; j < 4; ++j) { \
            int wv_ = s_wn[xbase[j] + poff_]; \
            const ushortT* src_ = (wv_ > 0) ? in_p + ((size_t)wv_ << 7) + cl8[j] : zerop; \
            gload16(src_, &s_x[bufi][(wid*64 + j*THREADS)*8]); \
        } \
    } else { \
        const size_t koff_ = (size_t)((kz_*PH + ky_)*PW + kx_)*CI + cib_; \
        _Pragma("unroll") for (int j = 0; j < 4; ++j) \
            gload16(in_p + xpre[j] + koff_, &s_x[bufi][(wid*64 + j*THREADS)*8]); \
    } }

#define COMPUTE(bufi) { \
    _Pragma("unroll") for (int ks = 0; ks < 4; ++ks) { \
        int cl_ = ks*4 + lq; \
        bf16x8 a0 = *(const bf16x8*)&s_w[bufi][aoff[0] + ((cl_ ^ axr[0])<<3)]; \
        bf16x8 a1 = *(const bf16x8*)&s_w[bufi][aoff[1] + ((cl_ ^ axr[1])<<3)]; \
        _Pragma("unroll") for (int f = 0; f < FRAG_N; ++f) { \
            bf16x8 bf = *(const bf16x8*)&s_x[bufi][boff[f] + ((cl_ ^ bxr[f])<<3)]; \
            acc[0][f] = __builtin_amdgcn_mfma_f32_16x16x32_bf16(a0, bf, acc[0][f],0,0,0); \
            acc[1][f] = __builtin_amdgcn_mfma_f32_16x16x32_bf16(a1, bf, acc[1][f],0,0,0); } } }

    STAGE(0, s0);
    __syncthreads();
    #pragma unroll
    for (int ph = 0; ph < SPB; ++ph) {
        const int buf = ph & 1;
        if (ph + 1 < SPB) STAGE(buf^1, s0 + ph + 1);
        COMPUTE(buf);
        __syncthreads();
    }
#undef STAGE
#undef COMPUTE

    if constexpr (!ATOMIC) {
        ushortT* out = (ushortT*)outp;   // [pos][CO] padded channels-last
        #pragma unroll
        for (int fm = 0; fm < 2; ++fm)
        #pragma unroll
        for (int fn = 0; fn < FRAG_N; ++fn) {
            int n = wn*(FRAG_N*16) + fn*16 + lr;
            int oy = n >> 3, ox = n & 7;
            int c_ = co0 + wm*32 + fm*16 + lq*4;
            size_t pa = ((size_t)(bz+1)*OPH + (oy0+oy+1))*OPW + (ox0+ox+1);
            ushort4 o;
            o.x = f2bf(acc[fm][fn][0]); o.y = f2bf(acc[fm][fn][1]);
            o.z = f2bf(acc[fm][fn][2]); o.w = f2bf(acc[fm][fn][3]);
            *(ushort4*)(out + pa*CO + c_) = o;
        }
        // fused BN stats (raw fp32 accumulators)
        #pragma unroll
        for (int fm = 0; fm < 2; ++fm) {
            float sv[4], qv[4];
            #pragma unroll
            for (int r = 0; r < 4; ++r) {
                float ssum = 0.f, qsum = 0.f;
                #pragma unroll
                for (int fn = 0; fn < FRAG_N; ++fn) {
                    float a = acc[fm][fn][r]; ssum += a; qsum += a*a;
                }
                #pragma unroll
                for (int m = 1; m < 16; m <<= 1) {
                    ssum += __shfl_xor(ssum, m, 64);
                    qsum += __shfl_xor(qsum, m, 64);
                }
                sv[r] = ssum; qv[r] = qsum;
            }
            if (lr == 0) {
                int c_ = co0 + wm*32 + fm*16 + lq*4;
                #pragma unroll
                for (int r = 0; r < 4; ++r) {
                    atomicAdd(&sums_out[c_+r], sv[r]);
                    atomicAdd(&sums_out[CO + c_+r], qv[r]);
                }
            }
        }
    } else {
        float* out = (float*)outp;       // channel-major fp32 (d_out)
        #pragma unroll
        for (int fm = 0; fm < 2; ++fm)
        #pragma unroll
        for (int fn = 0; fn < FRAG_N; ++fn) {
            int n = wn*(FRAG_N*16) + fn*16 + lr;
            int oy = n >> 3, ox = n & 7;
            int c_ = co0 + wm*32 + fm*16 + lq*4;
            #pragma unroll
            for (int r = 0; r < 4; ++r)
                atomicAdd(&out[((size_t)(c_+r)*DO + bz)*(HO*WO) + (oy0+oy)*WO + ox0+ox],
                          acc[fm][fn][r]);
        }
    }
}

// ---------------- BN apply in place on padded channels-last bf16 ------------
template<int C, int PD, int PH, int PW>
__global__ void bn_apply_pad(ushortT* __restrict__ y, const float* __restrict__ sums,
                             const float* __restrict__ g, const float* __restrict__ be,
                             float invN) {
    constexpr int CH = C/8;
    constexpr int total = PD*PH*PW*CH;
    __shared__ float s_sc[C], s_sh[C];
    for (int c = threadIdx.x; c < C; c += 256) {
        float mean = sums[c]*invN;
        float var  = sums[C+c]*invN - mean*mean;
        float sc = g[c]*rsqrtf(var + EPSBN);
        s_sc[c] = sc; s_sh[c] = be[c] - mean*sc;
    }
    __syncthreads();
    for (int e = blockIdx.x*256 + threadIdx.x; e < total; e += gridDim.x*256) {
        int pos = e / CH;
        int c0 = (e % CH)*8;
        int pz = pos / (PH*PW); int rr = pos % (PH*PW);
        int py = rr / PW; int px = rr % PW;
        if ((unsigned)(pz-1) >= (unsigned)(PD-2) || (unsigned)(py-1) >= (unsigned)(PH-2) ||
            (unsigned)(px-1) >= (unsigned)(PW-2)) continue;   // pads stay zero
        ushortT* p = y + (size_t)pos*C + c0;
        ushort4 a = *(ushort4*)p, b4 = *(ushort4*)(p+4);
        ushort4 o1, o2;
        o1.x = f2bf(fmaxf(0.f, bf2f(a.x)*s_sc[c0+0]+s_sh[c0+0]));
        o1.y = f2bf(fmaxf(0.f, bf2f(a.y)*s_sc[c0+1]+s_sh[c0+1]));
        o1.z = f2bf(fmaxf(0.f, bf2f(a.z)*s_sc[c0+2]+s_sh[c0+2]));
        o1.w = f2bf(fmaxf(0.f, bf2f(a.w)*s_sc[c0+3]+s_sh[c0+3]));
        o2.x = f2bf(fmaxf(0.f, bf2f(b4.x)*s_sc[c0+4]+s_sh[c0+4]));
        o2.y = f2bf(fmaxf(0.f, bf2f(b4.y)*s_sc[c0+5]+s_sh[c0+5]));
        o2.z = f2bf(fmaxf(0.f, bf2f(b4.z)*s_sc[c0+6]+s_sh[c0+6]));
        o2.w = f2bf(fmaxf(0.f, bf2f(b4.w)*s_sc[c0+7]+s_sh[c0+7]));
        *(ushort4*)p     = o1;
        *(ushort4*)(p+4) = o2;
    }
}

// ---------------- BN for channel-major fp32 (final output) -----------------
template<int SPL>
__global__ void bn_stats_cmajor(const float* __restrict__ y, const float* __restrict__ g,
                                const float* __restrict__ be, float* __restrict__ ss, int C) {
    __shared__ float s_red[2][256];
    int c = blockIdx.x;
    const float* p = y + (size_t)c*SPL;
    float sum = 0.f, sq = 0.f;
    for (int i = threadIdx.x; i < SPL; i += 256) { float v = p[i]; sum += v; sq += v*v; }
    s_red[0][threadIdx.x] = sum; s_red[1][threadIdx.x] = sq;
    __syncthreads();
    for (int s = 128; s > 0; s >>= 1) {
        if (threadIdx.x < s) {
            s_red[0][threadIdx.x] += s_red[0][threadIdx.x+s];
            s_red[1][threadIdx.x] += s_red[1][threadIdx.x+s];
        }
        __syncthreads();
    }
    if (threadIdx.x == 0) {
        float invN = 1.f/(float)SPL;
        float mean = s_red[0][0]*invN;
        float var  = s_red[1][0]*invN - mean*mean;
        float sc = g[c]*rsqrtf(var + EPSBN);
        ss[c] = sc; ss[C+c] = be[c] - mean*sc;
    }
}

template<int LOGSPL>
__global__ void bn_apply_cmajor(float* __restrict__ y, const float* __restrict__ ss,
                                int C, int total) {
    for (int i = blockIdx.x*blockDim.x + threadIdx.x; i < total; i += gridDim.x*blockDim.x) {
        int c = i >> LOGSPL;
        y[i] = fmaxf(0.f, y[i]*ss[c] + ss[C+c]);
    }
}

// ---------------- host launcher --------------------------------------------
extern "C" void kernel_launch(void* const* d_in, const int* in_sizes, int n_in,
                              void* d_out, int out_size, void* d_ws, size_t ws_size,
                              hipStream_t stream) {
    const float* x      = (const float*)d_in[0];
    const int*   coords = (const int*)  d_in[1];
    const float* w1  = (const float*)d_in[5];
    const float* g1  = (const float*)d_in[7];
    const float* be1 = (const float*)d_in[8];
    const float* w2  = (const float*)d_in[9];
    const float* g2  = (const float*)d_in[11];
    const float* be2 = (const float*)d_in[12];
    const float* cw1 = (const float*)d_in[13];
    const float* cg1 = (const float*)d_in[15];
    const float* cbe1= (const float*)d_in[16];
    const float* cw2 = (const float*)d_in[17];
    const float* cg2 = (const float*)d_in[19];
    const float* cbe2= (const float*)d_in[20];
    const float* cw3 = (const float*)d_in[21];
    const float* cg3 = (const float*)d_in[23];
    const float* cbe3= (const float*)d_in[24];
    float* out = (float*)d_out;

    // ---- workspace layout: [stats|winner|c1o|c2o] = one zero-memset region --
    float*   ws     = (float*)d_ws;
    float*   stats  = ws;                                    // 4096 f32 (16KB)
    int*     winner = (int*)(ws + 4096);                     // SP ints (1MB)
    ushortT* c1o    = (ushortT*)(winner + SP);               // PSP2*128 (11.15MB)
    ushortT* c2o    = c1o + (size_t)PSP2*128;                // PSP3*256 (3.55MB)
    float*   y2     = (float*)(c2o + (size_t)PSP3*256);      // 12000*128 f32
    ushortT* f2b    = (ushortT*)(y2 + (size_t)NVOX*C2);      // 12000*128 bf16
    ushortT* wb1    = f2b + (size_t)NVOX*C2;                 // 442368
    ushortT* wb2    = wb1 + 442368;                          // 884736
    ushortT* wb3    = wb2 + 884736;                          // 1769472

    float* s1sum = stats;          // 128
    float* s2sum = stats + 128;    // 256
    float* c1sum = stats + 384;    // 256
    float* c2sum = stats + 640;    // 512
    float* ss3   = stats + 1152;   // 512
    const ushortT* zerop = (const ushortT*)(stats + 2048);   // zeroed, never written

    const size_t zbytes = 4096*sizeof(float) + (size_t)SP*sizeof(int)
                        + (size_t)PSP2*128*2 + (size_t)PSP3*256*2;
    hipMemsetAsync(stats, 0, zbytes, stream);                 // stats+winner+c1o+c2o
    hipMemsetAsync(d_out, 0, (size_t)out_size*sizeof(float), stream);

    prep<<<2031, 256, 0, stream>>>(x, w1, s1sum, cw1, cw2, cw3, wb1, wb2, wb3,
                                   coords, winner);
    vfe12<<<NVOX/16, 256, 0, stream>>>(x, w1, s1sum, g1, be1, w2, y2, s2sum);
    vfe2_apply_bf16<<<NVOX*C2/4/256, 256, 0, stream>>>(y2, s2sum, g2, be2, f2b);

    // conv1: 128->128, GATHER from f2b (winner+1 indexing, in_p pre-offset -128)
    conv3d_mfma<128,128, 128,128,512, 1,1,1, 8,64,64, P2H,P2W, 27,1,false,true>
        <<<8*4*8, 512, 0, stream>>>(f2b - 128, wb1, c1o, c1sum, winner, zerop);
    bn_apply_pad<128, P2D,P2H,P2W><<<1024, 256, 0, stream>>>(c1o, c1sum, cg1, cbe1,
                                                             1.f/32768.f);
    // conv2: 128->256, c1o -> c2o(6,34,34); 64x64 tile, 256 blocks
    conv3d_mfma<128,256, 64,64,256, P2D,P2H,P2W, 4,32,32, P3H,P3W, 27,1,false,false>
        <<<4*4*4*4, 256, 0, stream>>>(c1o, wb2, c2o, c2sum, nullptr, nullptr);
    bn_apply_pad<256, P3D,P3H,P3W><<<512, 256, 0, stream>>>(c2o, c2sum, cg2, cbe2,
                                                            1.f/4096.f);
    // conv3: 256->256, c2o -> d_out fp32 cmajor; 54 phases, 6 slices, atomic
    conv3d_mfma<256,256, 64,64,256, P3D,P3H,P3W, 2,16,16, 1,1, 54,6,true,false>
        <<<2*2*2*4*6, 256, 0, stream>>>(c2o, wb3, (void*)out, nullptr, nullptr, nullptr);

    bn_stats_cmajor<2*16*16><<<256, 256, 0, stream>>>(out, cg3, cbe3, ss3, 256);
    bn_apply_cmajor<9><<<512, 256, 0, stream>>>(out, ss3, 256, 131072);
}

// Round 18
// 266.778 us; speedup vs baseline: 1.0322x; 1.0322x over previous
//
#include <hip/hip_runtime.h>

// ---------------- problem constants ----------------------------------------
#define NVOX 12000
#define NPTS 32
#define CIN  5
#define C1   64
#define C2   128
#define GD   16
#define GH   128
#define GW   128
#define SP   (GD*GH*GW)
static constexpr float EPSBN = 1e-5f;

typedef unsigned short ushortT;
typedef __attribute__((ext_vector_type(8))) short bf16x8;
typedef __attribute__((ext_vector_type(4))) float f32x4;

__device__ inline ushortT f2bf(float f) {
    unsigned int x = __float_as_uint(f);
    unsigned int r = (x + 0x7FFFu + ((x >> 16) & 1u)) >> 16;   // RNE
    return (ushortT)r;
}
__device__ inline float bf2f(ushortT u) { return __uint_as_float(((unsigned int)u) << 16); }

__device__ inline void gload16(const ushortT* g, ushortT* l) {
    __builtin_amdgcn_global_load_lds(
        (const __attribute__((address_space(1))) unsigned int*)g,
        (__attribute__((address_space(3))) unsigned int*)l, 16, 0, 0);
}

// padded spatial dims (channels-LAST layouts: [pos][C]) for conv2/conv3 inputs
#define P2D 10
#define P2H 66
#define P2W 66
#define PSP2 (P2D*P2H*P2W)
#define P3D 6
#define P3H 34
#define P3W 34
#define PSP3 (P3D*P3H*P3W)

// NOTE: biases are exact no-ops under training-mode BN (mean-subtracted).

// ---------------- prep: weight convert + vfe1 stats + scatter ---------------
// wb (BK=128): per phase a linear tile of TCO*16 chunks (16B); chunk p=(col,cp):
// content = w[cob*TCO+col][ci=(cp^(col&7))*8+j [+128 for CI=256 odd phase]]
__device__ inline void conv_w_one(const float* cw, ushortT* wb, int CI_, int TCO_,
                                  int NS_, int e) {
    int j = e & 7;
    int rest = e >> 3;
    int CHN = TCO_*16;
    int p = rest % CHN; int r = rest / CHN;
    int s = r % NS_;    int cob = r / NS_;
    int col = p >> 4, cp = p & 15;
    int cl = cp ^ (col & 7);
    int tap = (CI_==256) ? (s>>1) : s;
    int cib = (CI_==256) ? ((s&1)*128) : 0;
    int co = cob*TCO_ + col;
    int ci = cib + cl*8 + j;
    wb[e] = f2bf(cw[((size_t)co*CI_ + ci)*27 + tap]);
}

__global__ void prep(const float* __restrict__ x, const float* __restrict__ w1,
                     float* __restrict__ s1sum,
                     const float* __restrict__ cw1, const float* __restrict__ cw2,
                     const float* __restrict__ cw3, ushortT* __restrict__ wb1,
                     ushortT* __restrict__ wb2, ushortT* __restrict__ wb3,
                     const int* __restrict__ coords, int* __restrict__ winner) {
    __shared__ float s_w[CIN*C1];
    __shared__ float s_red[2][4][C1];
    const int blk = blockIdx.x;
    const int t = threadIdx.x;
    if (blk < 960) {
        for (int i = t; i < CIN*C1; i += 256) s_w[i] = w1[i];
        __syncthreads();
        int ch = t & 63, rr = t >> 6;
        float sum = 0.f, sq = 0.f;
        const int NROWS = NVOX * NPTS;
        for (int row = blk*4 + rr; row < NROWS; row += 960*4) {
            const float* xr = x + row*CIN;
            float y = 0.f;
            #pragma unroll
            for (int c = 0; c < CIN; ++c) y += xr[c] * s_w[c*C1 + ch];
            sum += y; sq += y*y;
        }
        s_red[0][rr][ch] = sum; s_red[1][rr][ch] = sq;
        __syncthreads();
        if (rr == 0) {
            sum = s_red[0][0][ch]+s_red[0][1][ch]+s_red[0][2][ch]+s_red[0][3][ch];
            sq  = s_red[1][0][ch]+s_red[1][1][ch]+s_red[1][2][ch]+s_red[1][3][ch];
            atomicAdd(&s1sum[ch], sum);
            atomicAdd(&s1sum[C1+ch], sq);
        }
    } else if (blk < 1984) {
        const int N1 = 442368, N2 = 884736, N3 = 1769472;
        const int total = N1+N2+N3;
        for (int e0 = (blk-960)*256 + t; e0 < total; e0 += 1024*256) {
            if (e0 < N1)         conv_w_one(cw1, wb1, 128, 128, 27, e0);
            else if (e0 < N1+N2) conv_w_one(cw2, wb2, 128, 64,  27, e0-N1);
            else                 conv_w_one(cw3, wb3, 256, 64,  54, e0-N1-N2);
        }
    } else {
        int v = (blk-1984)*256 + t;
        if (v < NVOX) {
            int d = coords[v*3+0], h = coords[v*3+1], w = coords[v*3+2];
            atomicMax(&winner[(d*GH + h)*GW + w], v);
        }
    }
}

// ---------------- VFE1 apply: 4 voxels per 256-thr block -------------------
__global__ void vfe1_apply(const float* __restrict__ x, const float* __restrict__ w1,
                           const float* __restrict__ sums, const float* __restrict__ g,
                           const float* __restrict__ be, float* __restrict__ f1) {
    __shared__ float s_w[CIN*C1];
    __shared__ float s_x[4*NPTS*CIN];
    int v0 = blockIdx.x*4, t = threadIdx.x;
    for (int i = t; i < CIN*C1; i += 256) s_w[i] = w1[i];
    for (int i = t; i < 4*NPTS*CIN; i += 256) s_x[i] = x[(size_t)v0*NPTS*CIN + i];
    int sub = t >> 6, ch = t & 63;
    const float invN = 1.f/(NVOX*NPTS);
    float mean = sums[ch]*invN;
    float var  = sums[C1+ch]*invN - mean*mean;
    float sc = g[ch]*rsqrtf(var + EPSBN);
    float sh = be[ch] - mean*sc;
    __syncthreads();
    float m = 0.f;
    const float* xs = s_x + sub*NPTS*CIN;
    for (int p = 0; p < NPTS; ++p) {
        float y = 0.f;
        #pragma unroll
        for (int c = 0; c < CIN; ++c) y += xs[p*CIN+c]*s_w[c*C1+ch];
        m = fmaxf(m, y*sc + sh);
    }
    f1[(v0+sub)*C1 + ch] = m;
}

// ---------------- VFE2 linear ----------------------------------------------
__global__ void vfe2_linear(const float* __restrict__ f1, const float* __restrict__ w2,
                            float* __restrict__ y2, float* __restrict__ sums) {
    __shared__ float s_w[C2][68];
    __shared__ float s_f[16*C1];
    int t = threadIdx.x; // 128
    for (int i = t; i < C1*C2; i += 128) {
        int c = i >> 7, o = i & 127;
        s_w[o][c] = w2[i];
    }
    int v0 = blockIdx.x*16;
    for (int i = t; i < 16*C1; i += 128) s_f[i] = f1[v0*C1 + i];
    __syncthreads();
    float sum = 0.f, sq = 0.f;
    for (int vl = 0; vl < 16; ++vl) {
        float y = 0.f;
        #pragma unroll
        for (int c4 = 0; c4 < C1; c4 += 4) {
            float4 f = *(const float4*)&s_f[vl*C1 + c4];
            float4 w = *(const float4*)&s_w[t][c4];
            y += f.x*w.x + f.y*w.y + f.z*w.z + f.w*w.w;
        }
        y2[(v0+vl)*C2 + t] = y;
        sum += y; sq += y*y;
    }
    atomicAdd(&sums[t], sum);
    atomicAdd(&sums[C2+t], sq);
}

__global__ void vfe2_apply_bf16(const float* __restrict__ y2, const float* __restrict__ sums,
                                const float* __restrict__ g, const float* __restrict__ be,
                                ushortT* __restrict__ f2b) {
    __shared__ float s_sc[C2], s_sh[C2];
    int t = threadIdx.x;
    if (t < C2) {
        const float invN = 1.f/NVOX;
        float mean = sums[t]*invN;
        float var  = sums[C2+t]*invN - mean*mean;
        float sc = g[t]*rsqrtf(var + EPSBN);
        s_sc[t] = sc; s_sh[t] = be[t] - mean*sc;
    }
    __syncthreads();
    int i = blockIdx.x*256 + t;
    if (i >= NVOX*C2/4) return;
    const float4 v = *(const float4*)(y2 + (size_t)i*4);
    int c0 = (i*4) & (C2-1);
    ushort4 o;
    o.x = f2bf(fmaxf(0.f, v.x*s_sc[c0+0]+s_sh[c0+0]));
    o.y = f2bf(fmaxf(0.f, v.y*s_sc[c0+1]+s_sh[c0+1]));
    o.z = f2bf(fmaxf(0.f, v.z*s_sc[c0+2]+s_sh[c0+2]));
    o.w = f2bf(fmaxf(0.f, v.w*s_sc[c0+3]+s_sh[c0+3]));
    *(ushort4*)(f2b + (size_t)i*4) = o;
}

// ---------------- conv3d as tap-GEMM (m97 skeleton; R16-proven) -------------
// GATHER mode (conv1): s_x sources are PER-LANE gathers from f2b via a
// LDS-cached winner halo; empty cells/pads point at a zeroed page.
template<int CI, int CO, int TILE_CO, int TILE_SP, int THREADS,
         int PD, int PH, int PW, int DO, int HO, int WO,
         int OPH, int OPW, int NS, int NSLICE, bool ATOMIC, bool GATHER>
__global__ __launch_bounds__(THREADS) void conv3d_mfma(
        const ushortT* __restrict__ in_p, const ushortT* __restrict__ wb,
        void* __restrict__ outp, float* __restrict__ sums_out,
        const int* __restrict__ winner, const ushortT* __restrict__ zerop) {
    constexpr int NW      = THREADS/64;
    constexpr int WAVES_M = TILE_CO/32;
    constexpr int WAVES_N = NW/WAVES_M;
    constexpr int FRAG_N  = TILE_SP/(WAVES_N*16);
    constexpr int TILE_Y  = TILE_SP/8;
    constexpr int SPB     = NS/NSLICE;
    constexpr int WCH     = TILE_CO*16;
    constexpr int NHALO   = 3*(2*TILE_Y+1)*17;

    __shared__ ushortT s_x[2][TILE_SP*128];
    __shared__ ushortT s_w[2][TILE_CO*128];
    __shared__ short   s_wn[GATHER ? NHALO : 2];

    constexpr int nbx = WO/8, nby = HO/TILE_Y;
    constexpr int NWG = nbx*nby*DO*(CO/TILE_CO)*NSLICE;
    int b = (blockIdx.x & 7)*(NWG >> 3) + (blockIdx.x >> 3);   // XCD swizzle
    const int bx = b % nbx; b /= nbx;
    const int by = b % nby; b /= nby;
    const int bz = b % DO;  b /= DO;
    const int cob   = b % (CO/TILE_CO);
    const int slice = b / (CO/TILE_CO);
    const int co0 = cob*TILE_CO;
    const int oy0 = by*TILE_Y, ox0 = bx*8;
    const int t = threadIdx.x;
    const int lane = t & 63, wid = t >> 6;
    const int lr = lane & 15, lq = lane >> 4;
    const int wm = wid % WAVES_M, wn = wid / WAVES_M;

    if constexpr (GATHER) {
        constexpr int HROW = 2*TILE_Y+1;
        for (int c = t; c < NHALO; c += THREADS) {
            int zz = c/(HROW*17), rr = c%(HROW*17), yy = rr/17, xx = rr%17;
            int iz = 2*bz-1+zz, iy = 2*oy0-1+yy, ix = 2*ox0-1+xx;
            int wv = -1;
            if ((unsigned)iz < (unsigned)GD && (unsigned)iy < (unsigned)GH &&
                (unsigned)ix < (unsigned)GW)
                wv = winner[(iz*GH + iy)*GW + ix];
            s_wn[c] = (short)wv;
        }
        __syncthreads();
    }

    // per-thread input-staging invariants
    size_t xpre[4]; int xbase[4]; int cl8[4];
    #pragma unroll
    for (int j = 0; j < 4; ++j) {
        int q = t + j*THREADS;
        int n = q >> 4, cp = q & 15;
        int cl = cp ^ (n & 7);
        int oy = n >> 3, ox = n & 7;
        if constexpr (GATHER) {
            xbase[j] = (2*oy)*17 + 2*ox;
            cl8[j]   = cl*8;
            xpre[j]  = 0;
        } else {
            xpre[j] = (size_t)(((2*bz)*PH + (2*oy0 + 2*oy))*PW + (2*ox0 + 2*ox))*CI + cl*8;
            xbase[j] = 0; cl8[j] = 0;
        }
    }
    // compute-side row bases
    int aoff[2], axr[2], boff[FRAG_N], bxr[FRAG_N];
    #pragma unroll
    for (int f = 0; f < 2; ++f) {
        int c = wm*32 + f*16 + lr;
        aoff[f] = c*128; axr[f] = c & 7;
    }
    #pragma unroll
    for (int f = 0; f < FRAG_N; ++f) {
        int n = wn*(FRAG_N*16) + f*16 + lr;
        boff[f] = n*128; bxr[f] = n & 7;
    }

    f32x4 acc[2][FRAG_N];
    #pragma unroll
    for (int i = 0; i < 2; ++i)
        #pragma unroll
        for (int j = 0; j < FRAG_N; ++j) acc[i][j] = (f32x4){0.f,0.f,0.f,0.f};

    const int s0 = slice*SPB;

#define STAGE(bufi, s) { \
    const int tap_ = (CI==256) ? ((s)>>1) : (s); \
    const int cib_ = (CI==256) ? (((s)&1)*128) : 0; \
    const int kz_ = tap_/9, ky_ = (tap_/3)%3, kx_ = tap_%3; \
    const ushortT* wsrc_ = wb + ((size_t)(cob*NS + (s)))*(WCH*8); \
    _Pragma("unroll") for (int j = 0; j < 4; ++j) \
        gload16(wsrc_ + (size_t)(t + j*THREADS)*8, &s_w[bufi][(wid*64 + j*THREADS)*8]); \
    if constexpr (GATHER) { \
        const int poff_ = kz_*((2*TILE_Y+1)*17) + ky_*17 + kx_; \
        _Pragma("unroll") for (int j = 0; j < 4; ++j) { \
            int wv_ = s_wn[xbase[j] + poff_]; \
            const ushortT* src_ = (wv_ >= 0) ? in_p + ((size_t)wv_ << 7) + cl8[j] : zerop; \
            gload16(src_, &s_x[bufi][(wid*64 + j*THREADS)*8]); \
        } \
    } else { \
        const size_t koff_ = (size_t)((kz_*PH + ky_)*PW + kx_)*CI + cib_; \
        _Pragma("unroll") for (int j = 0; j < 4; ++j) \
            gload16(in_p + xpre[j] + koff_, &s_x[bufi][(wid*64 + j*THREADS)*8]); \
    } }

#define COMPUTE(bufi) { \
    _Pragma("unroll") for (int ks = 0; ks < 4; ++ks) { \
        int cl_ = ks*4 + lq; \
        bf16x8 a0 = *(const bf16x8*)&s_w[bufi][aoff[0] + ((cl_ ^ axr[0])<<3)]; \
        bf16x8 a1 = *(const bf16x8*)&s_w[bufi][aoff[1] + ((cl_ ^ axr[1])<<3)]; \
        _Pragma("unroll") for (int f = 0; f < FRAG_N; ++f) { \
            bf16x8 bf = *(const bf16x8*)&s_x[bufi][boff[f] + ((cl_ ^ bxr[f])<<3)]; \
            acc[0][f] = __builtin_amdgcn_mfma_f32_16x16x32_bf16(a0, bf, acc[0][f],0,0,0); \
            acc[1][f] = __builtin_amdgcn_mfma_f32_16x16x32_bf16(a1, bf, acc[1][f],0,0,0); } } }

    STAGE(0, s0);
    __syncthreads();
    #pragma unroll
    for (int ph = 0; ph < SPB; ++ph) {
        const int buf = ph & 1;
        if (ph + 1 < SPB) STAGE(buf^1, s0 + ph + 1);
        COMPUTE(buf);
        __syncthreads();
    }
#undef STAGE
#undef COMPUTE

    if constexpr (!ATOMIC) {
        ushortT* out = (ushortT*)outp;   // [pos][CO] padded channels-last
        #pragma unroll
        for (int fm = 0; fm < 2; ++fm)
        #pragma unroll
        for (int fn = 0; fn < FRAG_N; ++fn) {
            int n = wn*(FRAG_N*16) + fn*16 + lr;
            int oy = n >> 3, ox = n & 7;
            int c_ = co0 + wm*32 + fm*16 + lq*4;
            size_t pa = ((size_t)(bz+1)*OPH + (oy0+oy+1))*OPW + (ox0+ox+1);
            ushort4 o;
            o.x = f2bf(acc[fm][fn][0]); o.y = f2bf(acc[fm][fn][1]);
            o.z = f2bf(acc[fm][fn][2]); o.w = f2bf(acc[fm][fn][3]);
            *(ushort4*)(out + pa*CO + c_) = o;
        }
        // fused BN stats (raw fp32 accumulators)
        #pragma unroll
        for (int fm = 0; fm < 2; ++fm) {
            float sv[4], qv[4];
            #pragma unroll
            for (int r = 0; r < 4; ++r) {
                float ssum = 0.f, qsum = 0.f;
                #pragma unroll
                for (int fn = 0; fn < FRAG_N; ++fn) {
                    float a = acc[fm][fn][r]; ssum += a; qsum += a*a;
                }
                #pragma unroll
                for (int m = 1; m < 16; m <<= 1) {
                    ssum += __shfl_xor(ssum, m, 64);
                    qsum += __shfl_xor(qsum, m, 64);
                }
                sv[r] = ssum; qv[r] = qsum;
            }
            if (lr == 0) {
                int c_ = co0 + wm*32 + fm*16 + lq*4;
                #pragma unroll
                for (int r = 0; r < 4; ++r) {
                    atomicAdd(&sums_out[c_+r], sv[r]);
                    atomicAdd(&sums_out[CO + c_+r], qv[r]);
                }
            }
        }
    } else {
        float* out = (float*)outp;       // channel-major fp32 (d_out)
        #pragma unroll
        for (int fm = 0; fm < 2; ++fm)
        #pragma unroll
        for (int fn = 0; fn < FRAG_N; ++fn) {
            int n = wn*(FRAG_N*16) + fn*16 + lr;
            int oy = n >> 3, ox = n & 7;
            int c_ = co0 + wm*32 + fm*16 + lq*4;
            #pragma unroll
            for (int r = 0; r < 4; ++r)
                atomicAdd(&out[((size_t)(c_+r)*DO + bz)*(HO*WO) + (oy0+oy)*WO + ox0+ox],
                          acc[fm][fn][r]);
        }
    }
}

// ---------------- BN apply in place on padded channels-last bf16 ------------
template<int C, int PD, int PH, int PW>
__global__ void bn_apply_pad(ushortT* __restrict__ y, const float* __restrict__ sums,
                             const float* __restrict__ g, const float* __restrict__ be,
                             float invN) {
    constexpr int CH = C/8;
    constexpr int total = PD*PH*PW*CH;
    __shared__ float s_sc[C], s_sh[C];
    for (int c = threadIdx.x; c < C; c += 256) {
        float mean = sums[c]*invN;
        float var  = sums[C+c]*invN - mean*mean;
        float sc = g[c]*rsqrtf(var + EPSBN);
        s_sc[c] = sc; s_sh[c] = be[c] - mean*sc;
    }
    __syncthreads();
    for (int e = blockIdx.x*256 + threadIdx.x; e < total; e += gridDim.x*256) {
        int pos = e / CH;
        int c0 = (e % CH)*8;
        int pz = pos / (PH*PW); int rr = pos % (PH*PW);
        int py = rr / PW; int px = rr % PW;
        if ((unsigned)(pz-1) >= (unsigned)(PD-2) || (unsigned)(py-1) >= (unsigned)(PH-2) ||
            (unsigned)(px-1) >= (unsigned)(PW-2)) continue;   // pads stay zero
        ushortT* p = y + (size_t)pos*C + c0;
        ushort4 a = *(ushort4*)p, b4 = *(ushort4*)(p+4);
        ushort4 o1, o2;
        o1.x = f2bf(fmaxf(0.f, bf2f(a.x)*s_sc[c0+0]+s_sh[c0+0]));
        o1.y = f2bf(fmaxf(0.f, bf2f(a.y)*s_sc[c0+1]+s_sh[c0+1]));
        o1.z = f2bf(fmaxf(0.f, bf2f(a.z)*s_sc[c0+2]+s_sh[c0+2]));
        o1.w = f2bf(fmaxf(0.f, bf2f(a.w)*s_sc[c0+3]+s_sh[c0+3]));
        o2.x = f2bf(fmaxf(0.f, bf2f(b4.x)*s_sc[c0+4]+s_sh[c0+4]));
        o2.y = f2bf(fmaxf(0.f, bf2f(b4.y)*s_sc[c0+5]+s_sh[c0+5]));
        o2.z = f2bf(fmaxf(0.f, bf2f(b4.z)*s_sc[c0+6]+s_sh[c0+6]));
        o2.w = f2bf(fmaxf(0.f, bf2f(b4.w)*s_sc[c0+7]+s_sh[c0+7]));
        *(ushort4*)p     = o1;
        *(ushort4*)(p+4) = o2;
    }
}

// ---------------- fused per-channel BN (stats + apply) for conv3 output -----
// Per-channel over SPL=512 elems: no cross-block dependency -> one kernel.
template<int SPL>
__global__ void bn_cmajor_fused(float* __restrict__ y, const float* __restrict__ g,
                                const float* __restrict__ be) {
    __shared__ float s_red[2][256];
    __shared__ float s_ss[2];
    int c = blockIdx.x;
    float* p = y + (size_t)c*SPL;
    int t = threadIdx.x;
    float v0 = p[t], v1 = p[t + 256];
    s_red[0][t] = v0 + v1;
    s_red[1][t] = v0*v0 + v1*v1;
    __syncthreads();
    for (int s = 128; s > 0; s >>= 1) {
        if (t < s) {
            s_red[0][t] += s_red[0][t+s];
            s_red[1][t] += s_red[1][t+s];
        }
        __syncthreads();
    }
    if (t == 0) {
        const float invN = 1.f/(float)SPL;
        float mean = s_red[0][0]*invN;
        float var  = s_red[1][0]*invN - mean*mean;
        float sc = g[c]*rsqrtf(var + EPSBN);
        s_ss[0] = sc; s_ss[1] = be[c] - mean*sc;
    }
    __syncthreads();
    float sc = s_ss[0], sh = s_ss[1];
    p[t]       = fmaxf(0.f, v0*sc + sh);
    p[t + 256] = fmaxf(0.f, v1*sc + sh);
}

// ---------------- host launcher --------------------------------------------
extern "C" void kernel_launch(void* const* d_in, const int* in_sizes, int n_in,
                              void* d_out, int out_size, void* d_ws, size_t ws_size,
                              hipStream_t stream) {
    const float* x      = (const float*)d_in[0];
    const int*   coords = (const int*)  d_in[1];
    const float* w1  = (const float*)d_in[5];
    const float* g1  = (const float*)d_in[7];
    const float* be1 = (const float*)d_in[8];
    const float* w2  = (const float*)d_in[9];
    const float* g2  = (const float*)d_in[11];
    const float* be2 = (const float*)d_in[12];
    const float* cw1 = (const float*)d_in[13];
    const float* cg1 = (const float*)d_in[15];
    const float* cbe1= (const float*)d_in[16];
    const float* cw2 = (const float*)d_in[17];
    const float* cg2 = (const float*)d_in[19];
    const float* cbe2= (const float*)d_in[20];
    const float* cw3 = (const float*)d_in[21];
    const float* cg3 = (const float*)d_in[23];
    const float* cbe3= (const float*)d_in[24];
    float* out = (float*)d_out;

    // ---- workspace layout ----
    float*   ws     = (float*)d_ws;
    float*   stats  = ws;                                    // 4096 f32 (zeroed)
    int*     winner = (int*)(ws + 4096);                     // SP
    float*   f1     = (float*)(winner + SP);                 // 12000*64
    float*   y2     = f1 + (size_t)NVOX*C1;                  // 12000*128
    ushortT* f2b    = (ushortT*)(y2 + (size_t)NVOX*C2);      // 12000*128
    ushortT* c1o    = f2b + (size_t)NVOX*C2;                 // PSP2*128
    ushortT* c2o    = c1o + (size_t)PSP2*128;                // PSP3*256
    ushortT* wb1    = c2o + (size_t)PSP3*256;                // 442368
    ushortT* wb2    = wb1 + 442368;                          // 884736
    ushortT* wb3    = wb2 + 884736;                          // 1769472

    float* s1sum = stats;          // 128
    float* s2sum = stats + 128;    // 256
    float* c1sum = stats + 384;    // 256
    float* c2sum = stats + 640;    // 512
    const ushortT* zerop = (const ushortT*)(stats + 2048);   // zeroed, never written

    hipMemsetAsync(stats, 0, 4096*sizeof(float), stream);
    hipMemsetAsync(winner, 0xFF, SP*sizeof(int), stream);
    hipMemsetAsync(c1o, 0, (size_t)PSP2*128*2, stream);
    hipMemsetAsync(c2o, 0, (size_t)PSP3*256*2, stream);
    hipMemsetAsync(d_out, 0, (size_t)out_size*sizeof(float), stream);

    prep<<<2031, 256, 0, stream>>>(x, w1, s1sum, cw1, cw2, cw3, wb1, wb2, wb3,
                                   coords, winner);
    vfe1_apply<<<NVOX/4, 256, 0, stream>>>(x, w1, s1sum, g1, be1, f1);
    vfe2_linear<<<NVOX/16, 128, 0, stream>>>(f1, w2, y2, s2sum);
    vfe2_apply_bf16<<<NVOX*C2/4/256, 256, 0, stream>>>(y2, s2sum, g2, be2, f2b);

    // conv1: 128->128, GATHER from f2b via winner halo -> c1o(10,66,66)
    conv3d_mfma<128,128, 128,128,512, 1,1,1, 8,64,64, P2H,P2W, 27,1,false,true>
        <<<8*4*8, 512, 0, stream>>>(f2b, wb1, c1o, c1sum, winner, zerop);
    bn_apply_pad<128, P2D,P2H,P2W><<<1024, 256, 0, stream>>>(c1o, c1sum, cg1, cbe1,
                                                             1.f/32768.f);
    // conv2: 128->256, c1o -> c2o(6,34,34); 64x64 tile, 256 blocks
    conv3d_mfma<128,256, 64,64,256, P2D,P2H,P2W, 4,32,32, P3H,P3W, 27,1,false,false>
        <<<4*4*4*4, 256, 0, stream>>>(c1o, wb2, c2o, c2sum, nullptr, nullptr);
    bn_apply_pad<256, P3D,P3H,P3W><<<512, 256, 0, stream>>>(c2o, c2sum, cg2, cbe2,
                                                            1.f/4096.f);
    // conv3: 256->256, c2o -> d_out fp32 cmajor; 54 phases, 6 slices, atomic
    conv3d_mfma<256,256, 64,64,256, P3D,P3H,P3W, 2,16,16, 1,1, 54,6,true,false>
        <<<2*2*2*4*6, 256, 0, stream>>>(c2o, wb3, (void*)out, nullptr, nullptr, nullptr);

    // fused per-channel BN on conv3 output (256 blocks, stats+apply in one)
    bn_cmajor_fused<2*16*16><<<256, 256, 0, stream>>>(out, cg3, cbe3);
}

// Round 19
// 256.347 us; speedup vs baseline: 1.0742x; 1.0407x over previous
//
#include <hip/hip_runtime.h>

// ---------------- problem constants ----------------------------------------
#define NVOX 12000
#define NPTS 32
#define CIN  5
#define C1   64
#define C2   128
#define GD   16
#define GH   128
#define GW   128
#define SP   (GD*GH*GW)
static constexpr float EPSBN = 1e-5f;

typedef unsigned short ushortT;
typedef __attribute__((ext_vector_type(8))) short bf16x8;
typedef __attribute__((ext_vector_type(4))) float f32x4;

__device__ inline ushortT f2bf(float f) {
    unsigned int x = __float_as_uint(f);
    unsigned int r = (x + 0x7FFFu + ((x >> 16) & 1u)) >> 16;   // RNE
    return (ushortT)r;
}
__device__ inline float bf2f(ushortT u) { return __uint_as_float(((unsigned int)u) << 16); }

__device__ inline void gload16(const ushortT* g, ushortT* l) {
    __builtin_amdgcn_global_load_lds(
        (const __attribute__((address_space(1))) unsigned int*)g,
        (__attribute__((address_space(3))) unsigned int*)l, 16, 0, 0);
}

// padded spatial dims (channels-LAST layouts: [pos][C]) for conv2/conv3 inputs
#define P2D 10
#define P2H 66
#define P2W 66
#define PSP2 (P2D*P2H*P2W)
#define P3D 6
#define P3H 34
#define P3W 34
#define PSP3 (P3D*P3H*P3W)

// NOTE: biases are exact no-ops under training-mode BN (mean-subtracted).

// ---------------- prep: weight convert + vfe1 stats + scatter ---------------
// wb (BK=128): per phase a linear tile of TCO*16 chunks (16B); chunk p=(col,cp):
// content = w[cob*TCO+col][ci=(cp^(col&7))*8+j [+128 for CI=256 odd phase]]
__device__ inline void conv_w_one(const float* cw, ushortT* wb, int CI_, int TCO_,
                                  int NS_, int e) {
    int j = e & 7;
    int rest = e >> 3;
    int CHN = TCO_*16;
    int p = rest % CHN; int r = rest / CHN;
    int s = r % NS_;    int cob = r / NS_;
    int col = p >> 4, cp = p & 15;
    int cl = cp ^ (col & 7);
    int tap = (CI_==256) ? (s>>1) : s;
    int cib = (CI_==256) ? ((s&1)*128) : 0;
    int co = cob*TCO_ + col;
    int ci = cib + cl*8 + j;
    wb[e] = f2bf(cw[((size_t)co*CI_ + ci)*27 + tap]);
}

__global__ void prep(const float* __restrict__ x, const float* __restrict__ w1,
                     float* __restrict__ s1sum,
                     const float* __restrict__ cw1, const float* __restrict__ cw2,
                     const float* __restrict__ cw3, ushortT* __restrict__ wb1,
                     ushortT* __restrict__ wb2, ushortT* __restrict__ wb3,
                     const int* __restrict__ coords, int* __restrict__ winner) {
    __shared__ float s_w[CIN*C1];
    __shared__ float s_red[2][4][C1];
    const int blk = blockIdx.x;
    const int t = threadIdx.x;
    if (blk < 960) {
        for (int i = t; i < CIN*C1; i += 256) s_w[i] = w1[i];
        __syncthreads();
        int ch = t & 63, rr = t >> 6;
        float sum = 0.f, sq = 0.f;
        const int NROWS = NVOX * NPTS;
        for (int row = blk*4 + rr; row < NROWS; row += 960*4) {
            const float* xr = x + row*CIN;
            float y = 0.f;
            #pragma unroll
            for (int c = 0; c < CIN; ++c) y += xr[c] * s_w[c*C1 + ch];
            sum += y; sq += y*y;
        }
        s_red[0][rr][ch] = sum; s_red[1][rr][ch] = sq;
        __syncthreads();
        if (rr == 0) {
            sum = s_red[0][0][ch]+s_red[0][1][ch]+s_red[0][2][ch]+s_red[0][3][ch];
            sq  = s_red[1][0][ch]+s_red[1][1][ch]+s_red[1][2][ch]+s_red[1][3][ch];
            atomicAdd(&s1sum[ch], sum);
            atomicAdd(&s1sum[C1+ch], sq);
        }
    } else if (blk < 1984) {
        const int N1 = 442368, N2 = 884736, N3 = 1769472;
        const int total = N1+N2+N3;
        for (int e0 = (blk-960)*256 + t; e0 < total; e0 += 1024*256) {
            if (e0 < N1)         conv_w_one(cw1, wb1, 128, 128, 27, e0);
            else if (e0 < N1+N2) conv_w_one(cw2, wb2, 128, 64,  27, e0-N1);
            else                 conv_w_one(cw3, wb3, 256, 64,  54, e0-N1-N2);
        }
    } else {
        int v = (blk-1984)*256 + t;
        if (v < NVOX) {
            int d = coords[v*3+0], h = coords[v*3+1], w = coords[v*3+2];
            atomicMax(&winner[(d*GH + h)*GW + w], v + 1);   // 0 = empty
        }
    }
}

// ---------------- VFE1 apply: 4 voxels per 256-thr block -------------------
__global__ void vfe1_apply(const float* __restrict__ x, const float* __restrict__ w1,
                           const float* __restrict__ sums, const float* __restrict__ g,
                           const float* __restrict__ be, float* __restrict__ f1) {
    __shared__ float s_w[CIN*C1];
    __shared__ float s_x[4*NPTS*CIN];
    int v0 = blockIdx.x*4, t = threadIdx.x;
    for (int i = t; i < CIN*C1; i += 256) s_w[i] = w1[i];
    for (int i = t; i < 4*NPTS*CIN; i += 256) s_x[i] = x[(size_t)v0*NPTS*CIN + i];
    int sub = t >> 6, ch = t & 63;
    const float invN = 1.f/(NVOX*NPTS);
    float mean = sums[ch]*invN;
    float var  = sums[C1+ch]*invN - mean*mean;
    float sc = g[ch]*rsqrtf(var + EPSBN);
    float sh = be[ch] - mean*sc;
    __syncthreads();
    float m = 0.f;
    const float* xs = s_x + sub*NPTS*CIN;
    for (int p = 0; p < NPTS; ++p) {
        float y = 0.f;
        #pragma unroll
        for (int c = 0; c < CIN; ++c) y += xs[p*CIN+c]*s_w[c*C1+ch];
        m = fmaxf(m, y*sc + sh);
    }
    f1[(v0+sub)*C1 + ch] = m;
}

// ---------------- VFE2 linear ----------------------------------------------
__global__ void vfe2_linear(const float* __restrict__ f1, const float* __restrict__ w2,
                            float* __restrict__ y2, float* __restrict__ sums) {
    __shared__ float s_w[C2][68];
    __shared__ float s_f[16*C1];
    int t = threadIdx.x; // 128
    for (int i = t; i < C1*C2; i += 128) {
        int c = i >> 7, o = i & 127;
        s_w[o][c] = w2[i];
    }
    int v0 = blockIdx.x*16;
    for (int i = t; i < 16*C1; i += 128) s_f[i] = f1[v0*C1 + i];
    __syncthreads();
    float sum = 0.f, sq = 0.f;
    for (int vl = 0; vl < 16; ++vl) {
        float y = 0.f;
        #pragma unroll
        for (int c4 = 0; c4 < C1; c4 += 4) {
            float4 f = *(const float4*)&s_f[vl*C1 + c4];
            float4 w = *(const float4*)&s_w[t][c4];
            y += f.x*w.x + f.y*w.y + f.z*w.z + f.w*w.w;
        }
        y2[(v0+vl)*C2 + t] = y;
        sum += y; sq += y*y;
    }
    atomicAdd(&sums[t], sum);
    atomicAdd(&sums[C2+t], sq);
}

__global__ void vfe2_apply_bf16(const float* __restrict__ y2, const float* __restrict__ sums,
                                const float* __restrict__ g, const float* __restrict__ be,
                                ushortT* __restrict__ f2b) {
    __shared__ float s_sc[C2], s_sh[C2];
    int t = threadIdx.x;
    if (t < C2) {
        const float invN = 1.f/NVOX;
        float mean = sums[t]*invN;
        float var  = sums[C2+t]*invN - mean*mean;
        float sc = g[t]*rsqrtf(var + EPSBN);
        s_sc[t] = sc; s_sh[t] = be[t] - mean*sc;
    }
    __syncthreads();
    int i = blockIdx.x*256 + t;
    if (i >= NVOX*C2/4) return;
    const float4 v = *(const float4*)(y2 + (size_t)i*4);
    int c0 = (i*4) & (C2-1);
    ushort4 o;
    o.x = f2bf(fmaxf(0.f, v.x*s_sc[c0+0]+s_sh[c0+0]));
    o.y = f2bf(fmaxf(0.f, v.y*s_sc[c0+1]+s_sh[c0+1]));
    o.z = f2bf(fmaxf(0.f, v.z*s_sc[c0+2]+s_sh[c0+2]));
    o.w = f2bf(fmaxf(0.f, v.w*s_sc[c0+3]+s_sh[c0+3]));
    *(ushort4*)(f2b + (size_t)i*4) = o;
}

// ---------------- conv3d as tap-GEMM (m97 skeleton; R16/R18-proven) ---------
// GATHER mode (conv1): s_x sources are PER-LANE gathers from f2b (in_p is
// pre-offset by -128 so winner+1 indexes directly); empty/pad -> zero page.
template<int CI, int CO, int TILE_CO, int TILE_SP, int THREADS,
         int PD, int PH, int PW, int DO, int HO, int WO,
         int OPH, int OPW, int NS, int NSLICE, bool ATOMIC, bool GATHER>
__global__ __launch_bounds__(THREADS) void conv3d_mfma(
        const ushortT* __restrict__ in_p, const ushortT* __restrict__ wb,
        void* __restrict__ outp, float* __restrict__ sums_out,
        const int* __restrict__ winner, const ushortT* __restrict__ zerop) {
    constexpr int NW      = THREADS/64;
    constexpr int WAVES_M = TILE_CO/32;
    constexpr int WAVES_N = NW/WAVES_M;
    constexpr int FRAG_N  = TILE_SP/(WAVES_N*16);
    constexpr int TILE_Y  = TILE_SP/8;
    constexpr int SPB     = NS/NSLICE;
    constexpr int WCH     = TILE_CO*16;
    constexpr int NHALO   = 3*(2*TILE_Y+1)*17;

    __shared__ ushortT s_x[2][TILE_SP*128];
    __shared__ ushortT s_w[2][TILE_CO*128];
    __shared__ short   s_wn[GATHER ? NHALO : 2];

    constexpr int nbx = WO/8, nby = HO/TILE_Y;
    constexpr int NWG = nbx*nby*DO*(CO/TILE_CO)*NSLICE;
    int b = (blockIdx.x & 7)*(NWG >> 3) + (blockIdx.x >> 3);   // XCD swizzle
    const int bx = b % nbx; b /= nbx;
    const int by = b % nby; b /= nby;
    const int bz = b % DO;  b /= DO;
    const int cob   = b % (CO/TILE_CO);
    const int slice = b / (CO/TILE_CO);
    const int co0 = cob*TILE_CO;
    const int oy0 = by*TILE_Y, ox0 = bx*8;
    const int t = threadIdx.x;
    const int lane = t & 63, wid = t >> 6;
    const int lr = lane & 15, lq = lane >> 4;
    const int wm = wid % WAVES_M, wn = wid / WAVES_M;

    if constexpr (GATHER) {
        constexpr int HROW = 2*TILE_Y+1;
        for (int c = t; c < NHALO; c += THREADS) {
            int zz = c/(HROW*17), rr = c%(HROW*17), yy = rr/17, xx = rr%17;
            int iz = 2*bz-1+zz, iy = 2*oy0-1+yy, ix = 2*ox0-1+xx;
            int wv = 0;
            if ((unsigned)iz < (unsigned)GD && (unsigned)iy < (unsigned)GH &&
                (unsigned)ix < (unsigned)GW)
                wv = winner[(iz*GH + iy)*GW + ix];
            s_wn[c] = (short)wv;
        }
        __syncthreads();
    }

    // per-thread input-staging invariants
    size_t xpre[4]; int xbase[4]; int cl8[4];
    #pragma unroll
    for (int j = 0; j < 4; ++j) {
        int q = t + j*THREADS;
        int n = q >> 4, cp = q & 15;
        int cl = cp ^ (n & 7);
        int oy = n >> 3, ox = n & 7;
        if constexpr (GATHER) {
            xbase[j] = (2*oy)*17 + 2*ox;
            cl8[j]   = cl*8;
            xpre[j]  = 0;
        } else {
            xpre[j] = (size_t)(((2*bz)*PH + (2*oy0 + 2*oy))*PW + (2*ox0 + 2*ox))*CI + cl*8;
            xbase[j] = 0; cl8[j] = 0;
        }
    }
    // compute-side row bases
    int aoff[2], axr[2], boff[FRAG_N], bxr[FRAG_N];
    #pragma unroll
    for (int f = 0; f < 2; ++f) {
        int c = wm*32 + f*16 + lr;
        aoff[f] = c*128; axr[f] = c & 7;
    }
    #pragma unroll
    for (int f = 0; f < FRAG_N; ++f) {
        int n = wn*(FRAG_N*16) + f*16 + lr;
        boff[f] = n*128; bxr[f] = n & 7;
    }

    f32x4 acc[2][FRAG_N];
    #pragma unroll
    for (int i = 0; i < 2; ++i)
        #pragma unroll
        for (int j = 0; j < FRAG_N; ++j) acc[i][j] = (f32x4){0.f,0.f,0.f,0.f};

    const int s0 = slice*SPB;

#define STAGE(bufi, s) { \
    const int tap_ = (CI==256) ? ((s)>>1) : (s); \
    const int cib_ = (CI==256) ? (((s)&1)*128) : 0; \
    const int kz_ = tap_/9, ky_ = (tap_/3)%3, kx_ = tap_%3; \
    const ushortT* wsrc_ = wb + ((size_t)(cob*NS + (s)))*(WCH*8); \
    _Pragma("unroll") for (int j = 0; j < 4; ++j) \
        gload16(wsrc_ + (size_t)(t + j*THREADS)*8, &s_w[bufi][(wid*64 + j*THREADS)*8]); \
    if constexpr (GATHER) { \
        const int poff_ = kz_*((2*TILE_Y+1)*17) + ky_*17 + kx_; \
        _Pragma("unroll") for (int j = 0; j < 4; ++j) { \
            int wv_ = s_wn[xbase[j] + poff_]; \
            const ushortT* src_ = (wv_ > 0) ? in_p + ((size_t)wv_ << 7) + cl8[j] : zerop; \
            gload16(src_, &s_x[bufi][(wid*64 + j*THREADS)*8]); \
        } \
    } else { \
        const size_t koff_ = (size_t)((kz_*PH + ky_)*PW + kx_)*CI + cib_; \
        _Pragma("unroll") for (int j = 0; j < 4; ++j) \
            gload16(in_p + xpre[j] + koff_, &s_x[bufi][(wid*64 + j*THREADS)*8]); \
    } }

#define COMPUTE(bufi) { \
    _Pragma("unroll") for (int ks = 0; ks < 4; ++ks) { \
        int cl_ = ks*4 + lq; \
        bf16x8 a0 = *(const bf16x8*)&s_w[bufi][aoff[0] + ((cl_ ^ axr[0])<<3)]; \
        bf16x8 a1 = *(const bf16x8*)&s_w[bufi][aoff[1] + ((cl_ ^ axr[1])<<3)]; \
        _Pragma("unroll") for (int f = 0; f < FRAG_N; ++f) { \
            bf16x8 bf = *(const bf16x8*)&s_x[bufi][boff[f] + ((cl_ ^ bxr[f])<<3)]; \
            acc[0][f] = __builtin_amdgcn_mfma_f32_16x16x32_bf16(a0, bf, acc[0][f],0,0,0); \
            acc[1][f] = __builtin_amdgcn_mfma_f32_16x16x32_bf16(a1, bf, acc[1][f],0,0,0); } } }

    STAGE(0, s0);
    __syncthreads();
    #pragma unroll
    for (int ph = 0; ph < SPB; ++ph) {
        const int buf = ph & 1;
        if (ph + 1 < SPB) STAGE(buf^1, s0 + ph + 1);
        COMPUTE(buf);
        __syncthreads();
    }
#undef STAGE
#undef COMPUTE

    if constexpr (!ATOMIC) {
        ushortT* out = (ushortT*)outp;   // [pos][CO] padded channels-last
        #pragma unroll
        for (int fm = 0; fm < 2; ++fm)
        #pragma unroll
        for (int fn = 0; fn < FRAG_N; ++fn) {
            int n = wn*(FRAG_N*16) + fn*16 + lr;
            int oy = n >> 3, ox = n & 7;
            int c_ = co0 + wm*32 + fm*16 + lq*4;
            size_t pa = ((size_t)(bz+1)*OPH + (oy0+oy+1))*OPW + (ox0+ox+1);
            ushort4 o;
            o.x = f2bf(acc[fm][fn][0]); o.y = f2bf(acc[fm][fn][1]);
            o.z = f2bf(acc[fm][fn][2]); o.w = f2bf(acc[fm][fn][3]);
            *(ushort4*)(out + pa*CO + c_) = o;
        }
        // fused BN stats (raw fp32 accumulators)
        #pragma unroll
        for (int fm = 0; fm < 2; ++fm) {
            float sv[4], qv[4];
            #pragma unroll
            for (int r = 0; r < 4; ++r) {
                float ssum = 0.f, qsum = 0.f;
                #pragma unroll
                for (int fn = 0; fn < FRAG_N; ++fn) {
                    float a = acc[fm][fn][r]; ssum += a; qsum += a*a;
                }
                #pragma unroll
                for (int m = 1; m < 16; m <<= 1) {
                    ssum += __shfl_xor(ssum, m, 64);
                    qsum += __shfl_xor(qsum, m, 64);
                }
                sv[r] = ssum; qv[r] = qsum;
            }
            if (lr == 0) {
                int c_ = co0 + wm*32 + fm*16 + lq*4;
                #pragma unroll
                for (int r = 0; r < 4; ++r) {
                    atomicAdd(&sums_out[c_+r], sv[r]);
                    atomicAdd(&sums_out[CO + c_+r], qv[r]);
                }
            }
        }
    } else {
        float* out = (float*)outp;       // channel-major fp32 (d_out)
        #pragma unroll
        for (int fm = 0; fm < 2; ++fm)
        #pragma unroll
        for (int fn = 0; fn < FRAG_N; ++fn) {
            int n = wn*(FRAG_N*16) + fn*16 + lr;
            int oy = n >> 3, ox = n & 7;
            int c_ = co0 + wm*32 + fm*16 + lq*4;
            #pragma unroll
            for (int r = 0; r < 4; ++r)
                atomicAdd(&out[((size_t)(c_+r)*DO + bz)*(HO*WO) + (oy0+oy)*WO + ox0+ox],
                          acc[fm][fn][r]);
        }
    }
}

// ---------------- BN apply in place on padded channels-last bf16 ------------
template<int C, int PD, int PH, int PW>
__global__ void bn_apply_pad(ushortT* __restrict__ y, const float* __restrict__ sums,
                             const float* __restrict__ g, const float* __restrict__ be,
                             float invN) {
    constexpr int CH = C/8;
    constexpr int total = PD*PH*PW*CH;
    __shared__ float s_sc[C], s_sh[C];
    for (int c = threadIdx.x; c < C; c += 256) {
        float mean = sums[c]*invN;
        float var  = sums[C+c]*invN - mean*mean;
        float sc = g[c]*rsqrtf(var + EPSBN);
        s_sc[c] = sc; s_sh[c] = be[c] - mean*sc;
    }
    __syncthreads();
    for (int e = blockIdx.x*256 + threadIdx.x; e < total; e += gridDim.x*256) {
        int pos = e / CH;
        int c0 = (e % CH)*8;
        int pz = pos / (PH*PW); int rr = pos % (PH*PW);
        int py = rr / PW; int px = rr % PW;
        if ((unsigned)(pz-1) >= (unsigned)(PD-2) || (unsigned)(py-1) >= (unsigned)(PH-2) ||
            (unsigned)(px-1) >= (unsigned)(PW-2)) continue;   // pads stay zero
        ushortT* p = y + (size_t)pos*C + c0;
        ushort4 a = *(ushort4*)p, b4 = *(ushort4*)(p+4);
        ushort4 o1, o2;
        o1.x = f2bf(fmaxf(0.f, bf2f(a.x)*s_sc[c0+0]+s_sh[c0+0]));
        o1.y = f2bf(fmaxf(0.f, bf2f(a.y)*s_sc[c0+1]+s_sh[c0+1]));
        o1.z = f2bf(fmaxf(0.f, bf2f(a.z)*s_sc[c0+2]+s_sh[c0+2]));
        o1.w = f2bf(fmaxf(0.f, bf2f(a.w)*s_sc[c0+3]+s_sh[c0+3]));
        o2.x = f2bf(fmaxf(0.f, bf2f(b4.x)*s_sc[c0+4]+s_sh[c0+4]));
        o2.y = f2bf(fmaxf(0.f, bf2f(b4.y)*s_sc[c0+5]+s_sh[c0+5]));
        o2.z = f2bf(fmaxf(0.f, bf2f(b4.z)*s_sc[c0+6]+s_sh[c0+6]));
        o2.w = f2bf(fmaxf(0.f, bf2f(b4.w)*s_sc[c0+7]+s_sh[c0+7]));
        *(ushort4*)p     = o1;
        *(ushort4*)(p+4) = o2;
    }
}

// ---------------- fused per-channel BN (stats + apply) for conv3 output -----
template<int SPL>
__global__ void bn_cmajor_fused(float* __restrict__ y, const float* __restrict__ g,
                                const float* __restrict__ be) {
    __shared__ float s_red[2][256];
    __shared__ float s_ss[2];
    int c = blockIdx.x;
    float* p = y + (size_t)c*SPL;
    int t = threadIdx.x;
    float v0 = p[t], v1 = p[t + 256];
    s_red[0][t] = v0 + v1;
    s_red[1][t] = v0*v0 + v1*v1;
    __syncthreads();
    for (int s = 128; s > 0; s >>= 1) {
        if (t < s) {
            s_red[0][t] += s_red[0][t+s];
            s_red[1][t] += s_red[1][t+s];
        }
        __syncthreads();
    }
    if (t == 0) {
        const float invN = 1.f/(float)SPL;
        float mean = s_red[0][0]*invN;
        float var  = s_red[1][0]*invN - mean*mean;
        float sc = g[c]*rsqrtf(var + EPSBN);
        s_ss[0] = sc; s_ss[1] = be[c] - mean*sc;
    }
    __syncthreads();
    float sc = s_ss[0], sh = s_ss[1];
    p[t]       = fmaxf(0.f, v0*sc + sh);
    p[t + 256] = fmaxf(0.f, v1*sc + sh);
}

// ---------------- host launcher --------------------------------------------
extern "C" void kernel_launch(void* const* d_in, const int* in_sizes, int n_in,
                              void* d_out, int out_size, void* d_ws, size_t ws_size,
                              hipStream_t stream) {
    const float* x      = (const float*)d_in[0];
    const int*   coords = (const int*)  d_in[1];
    const float* w1  = (const float*)d_in[5];
    const float* g1  = (const float*)d_in[7];
    const float* be1 = (const float*)d_in[8];
    const float* w2  = (const float*)d_in[9];
    const float* g2  = (const float*)d_in[11];
    const float* be2 = (const float*)d_in[12];
    const float* cw1 = (const float*)d_in[13];
    const float* cg1 = (const float*)d_in[15];
    const float* cbe1= (const float*)d_in[16];
    const float* cw2 = (const float*)d_in[17];
    const float* cg2 = (const float*)d_in[19];
    const float* cbe2= (const float*)d_in[20];
    const float* cw3 = (const float*)d_in[21];
    const float* cg3 = (const float*)d_in[23];
    const float* cbe3= (const float*)d_in[24];
    float* out = (float*)d_out;

    // ---- workspace layout: [stats|winner|c1o|c2o] = one zero-memset region --
    float*   ws     = (float*)d_ws;
    float*   stats  = ws;                                    // 4096 f32 (16KB)
    int*     winner = (int*)(ws + 4096);                     // SP ints (1MB)
    ushortT* c1o    = (ushortT*)(winner + SP);               // PSP2*128
    ushortT* c2o    = c1o + (size_t)PSP2*128;                // PSP3*256
    float*   f1     = (float*)(c2o + (size_t)PSP3*256);      // 12000*64 f32
    float*   y2     = f1 + (size_t)NVOX*C1;                  // 12000*128 f32
    ushortT* f2b    = (ushortT*)(y2 + (size_t)NVOX*C2);      // 12000*128 bf16
    ushortT* wb1    = f2b + (size_t)NVOX*C2;                 // 442368
    ushortT* wb2    = wb1 + 442368;                          // 884736
    ushortT* wb3    = wb2 + 884736;                          // 1769472

    float* s1sum = stats;          // 128
    float* s2sum = stats + 128;    // 256
    float* c1sum = stats + 384;    // 256
    float* c2sum = stats + 640;    // 512
    const ushortT* zerop = (const ushortT*)(stats + 2048);   // zeroed, never written

    const size_t zbytes = 4096*sizeof(float) + (size_t)SP*sizeof(int)
                        + (size_t)PSP2*128*2 + (size_t)PSP3*256*2;
    hipMemsetAsync(stats, 0, zbytes, stream);                 // stats+winner+c1o+c2o
    hipMemsetAsync(d_out, 0, (size_t)out_size*sizeof(float), stream);

    prep<<<2031, 256, 0, stream>>>(x, w1, s1sum, cw1, cw2, cw3, wb1, wb2, wb3,
                                   coords, winner);
    vfe1_apply<<<NVOX/4, 256, 0, stream>>>(x, w1, s1sum, g1, be1, f1);
    vfe2_linear<<<NVOX/16, 128, 0, stream>>>(f1, w2, y2, s2sum);
    vfe2_apply_bf16<<<NVOX*C2/4/256, 256, 0, stream>>>(y2, s2sum, g2, be2, f2b);

    // conv1: 128->128, GATHER from f2b (winner+1 indexing, in_p pre-offset -128)
    conv3d_mfma<128,128, 128,128,512, 1,1,1, 8,64,64, P2H,P2W, 27,1,false,true>
        <<<8*4*8, 512, 0, stream>>>(f2b - 128, wb1, c1o, c1sum, winner, zerop);
    bn_apply_pad<128, P2D,P2H,P2W><<<1024, 256, 0, stream>>>(c1o, c1sum, cg1, cbe1,
                                                             1.f/32768.f);
    // conv2: 128->256, c1o -> c2o(6,34,34); 64x64 tile, 256 blocks
    conv3d_mfma<128,256, 64,64,256, P2D,P2H,P2W, 4,32,32, P3H,P3W, 27,1,false,false>
        <<<4*4*4*4, 256, 0, stream>>>(c1o, wb2, c2o, c2sum, nullptr, nullptr);
    bn_apply_pad<256, P3D,P3H,P3W><<<512, 256, 0, stream>>>(c2o, c2sum, cg2, cbe2,
                                                            1.f/4096.f);
    // conv3: 256->256, c2o -> d_out fp32 cmajor; 54 phases, 6 slices, atomic
    conv3d_mfma<256,256, 64,64,256, P3D,P3H,P3W, 2,16,16, 1,1, 54,6,true,false>
        <<<2*2*2*4*6, 256, 0, stream>>>(c2o, wb3, (void*)out, nullptr, nullptr, nullptr);

    // fused per-channel BN on conv3 output (256 blocks, stats+apply in one)
    bn_cmajor_fused<2*16*16><<<256, 256, 0, stream>>>(out, cg3, cbe3);
}